// Round 4
// baseline (288.244 us; speedup 1.0000x reference)
//
#include <hip/hip_runtime.h>
#include <math.h>

#define DD 768
#define HH 16
#define DHH 48
#define NPOS 512
#define NIDX 2048
#define INV_SCALE 0.14433756729740643f   // 1/sqrt(768/16)
#define LN_EPS 1e-5f

typedef __bf16 bf16_t;
typedef __bf16 bf16x8 __attribute__((ext_vector_type(8)));
typedef float f32x4 __attribute__((ext_vector_type(4)));

__device__ __forceinline__ void g2lds16(const void* g, void* l) {
  __builtin_amdgcn_global_load_lds((const __attribute__((address_space(1))) void*)g,
                                   (__attribute__((address_space(3))) void*)l, 16, 0, 0);
}

// ---------------------------------------------------------------------------
// prep: blocks 0-5 hist | 6-581 fp32->bf16 cvt | 582-773 content-bias GEMV
// ---------------------------------------------------------------------------
struct CvtDesc { const float* src; bf16_t* dst; int n8; };
struct CvtBatch { CvtDesc d[9]; };

__global__ __launch_bounds__(256) void prep(const int* __restrict__ fpos,
                                            const int* __restrict__ tpos,
                                            int* __restrict__ CNT, CvtBatch cvb,
                                            const float* __restrict__ hs,
                                            const float* __restrict__ Wcb0,
                                            const float* __restrict__ Wcb1,
                                            float* __restrict__ cbG) {
  const int bid = blockIdx.x;
  const int tid = threadIdx.x;
  __shared__ int shist[NPOS];
  if (bid < 6) {
    const int b = bid >> 1, which = bid & 1;
    const int* src = (which ? tpos : fpos) + b * NIDX;
    for (int i = tid; i < NPOS; i += 256) shist[i] = 0;
    __syncthreads();
    for (int i = tid; i < NIDX; i += 256) atomicAdd(&shist[src[i] & (NPOS - 1)], 1);
    __syncthreads();
    for (int i = tid; i < NPOS; i += 256) CNT[bid * NPOS + i] = shist[i];
  } else if (bid < 582) {
    const CvtDesc de = cvb.d[(bid - 6) >> 6];
    for (int i = ((bid - 6) & 63) * 256 + tid; i < de.n8; i += 64 * 256) {
      const f32x4 a = *(const f32x4*)(de.src + (size_t)i * 8);
      const f32x4 b = *(const f32x4*)(de.src + (size_t)i * 8 + 4);
      bf16_t t[8];
#pragma unroll
      for (int e = 0; e < 4; ++e) { t[e] = (bf16_t)a[e]; t[4 + e] = (bf16_t)b[e]; }
      *(bf16x8*)(de.dst + (size_t)i * 8) = *(bf16x8*)t;
    }
  } else {
    const int g = bid - 582;               // 6*32
    const int pd = g >> 5, t0 = (g & 31) * 16;
    const int b = pd >> 1;
    const float* W = (pd & 1) ? Wcb1 : Wcb0;
    const int tl = tid >> 4, hh = tid & 15;
    const float* hrow = hs + ((size_t)b * NPOS + t0 + tl) * DD;
    const float* wrow = W + hh * DD;
    float s = 0.f;
    for (int k = 0; k < DD; k += 4) {
      const f32x4 a = *(const f32x4*)(hrow + k);
      const f32x4 bq = *(const f32x4*)(wrow + k);
      s += a[0] * bq[0] + a[1] * bq[1] + a[2] * bq[2] + a[3] * bq[3];
    }
    cbG[((size_t)pd * NPOS + t0 + tl) * HH + hh] = s;
  }
}

// ---------------------------------------------------------------------------
// MFMA GEMM, 64x128 tile, dbuf single-barrier, 4 blocks/CU.
// C[512 x 768] = A[512 x 768]bf16 @ B[768 x 768]bf16^T + bias
// mode: 0 = f32 out, 1 = bf16 out, 2 = bf16 transposed out (C[col*512+row])
// ---------------------------------------------------------------------------
struct MDesc { const bf16_t* A; const bf16_t* B; const float* bias; void* C; int mode; };
struct MBatch { MDesc d[18]; };

__global__ __launch_bounds__(256, 4) void gemm64(MBatch batch) {
  const MDesc de = batch.d[blockIdx.y];
  const int mt = blockIdx.x & 7, nt = blockIdx.x >> 3;   // 8 x 6
  const int m0 = mt * 64, n0 = nt * 128;

  __shared__ bf16_t SA[2][2048];   // [64][32] packed
  __shared__ bf16_t SB[2][4096];   // [128][32] packed

  const int tid = threadIdx.x;
  const int w = tid >> 6, lane = tid & 63;
  const int wm = w >> 1, wn = w & 1;
  const int lm = lane & 15, lq = lane >> 4;
  const int sr = lane >> 2, sq = lane & 3;

  f32x4 acc[2][4] = {};

  auto stage = [&](int buf, int k0) {
#pragma unroll
    for (int c = 0; c < 3; ++c) {
      const int issue = w + c * 4;           // 0..11, wave-uniform
      if (issue < 4)
        g2lds16(de.A + (size_t)(m0 + issue * 16 + sr) * 768 + k0 + sq * 8,
                SA[buf] + issue * 512);
      else {
        const int e = issue - 4;
        g2lds16(de.B + (size_t)(n0 + e * 16 + sr) * 768 + k0 + sq * 8,
                SB[buf] + e * 512);
      }
    }
  };

  stage(0, 0);
  for (int k0i = 0; k0i < 24; ++k0i) {
    const int cur = k0i & 1;
    __syncthreads();
    if (k0i + 1 < 24) stage(cur ^ 1, (k0i + 1) * 32);
    bf16x8 af[2], bfr[4];
#pragma unroll
    for (int i = 0; i < 2; ++i)
      af[i] = *(const bf16x8*)(SA[cur] + (wm * 32 + i * 16 + lm) * 32 + lq * 8);
#pragma unroll
    for (int j = 0; j < 4; ++j)
      bfr[j] = *(const bf16x8*)(SB[cur] + (wn * 64 + j * 16 + lm) * 32 + lq * 8);
#pragma unroll
    for (int i = 0; i < 2; ++i)
#pragma unroll
      for (int j = 0; j < 4; ++j)
        acc[i][j] = __builtin_amdgcn_mfma_f32_16x16x32_bf16(af[i], bfr[j], acc[i][j], 0, 0, 0);
  }

#pragma unroll
  for (int i = 0; i < 2; ++i) {
    const int rbase = m0 + wm * 32 + i * 16 + lq * 4;
#pragma unroll
    for (int j = 0; j < 4; ++j) {
      const int c = n0 + wn * 64 + j * 16 + lm;
      const float bv = de.bias ? de.bias[c] : 0.f;
#pragma unroll
      for (int r = 0; r < 4; ++r) {
        const float v = acc[i][j][r] + bv;
        if (de.mode == 0)      ((float*)de.C)[(size_t)(rbase + r) * 768 + c] = v;
        else if (de.mode == 1) ((bf16_t*)de.C)[(size_t)(rbase + r) * 768 + c] = (bf16_t)v;
        else                   ((bf16_t*)de.C)[(size_t)c * NPOS + rbase + r] = (bf16_t)v;
      }
    }
  }
}

// ---------------------------------------------------------------------------
// Fused MFMA attention per (pd, h, 64-row f-tile).
// Union LDS: staging dbuf (At/Bt) shares space with P/Vs -> 40.2 KB, 4 blk/CU.
// Single-barrier dbuf k0 loop; mix (pre-scaled by INV_SCALE) at A-fragment;
// count folded via log; PV via MFMA with ones-row giving the denominator.
// ---------------------------------------------------------------------------
__global__ __launch_bounds__(256, 4) void attn_mfma(
    const bf16_t* __restrict__ Qg, const bf16_t* __restrict__ Kg,
    const bf16_t* __restrict__ Vt, const float* __restrict__ cbG,
    const int* __restrict__ CNT, const float* __restrict__ mix0,
    const float* __restrict__ mix1, bf16_t* __restrict__ CTX) {
  const int bid = blockIdx.x;             // 6*16*8 = 768
  const int ft = bid & 7, h = (bid >> 3) & 15, pd = bid >> 7;
  const int dir = pd & 1;
  const int f0 = ft * 64;

  // Union buffer, bf16 elems:
  //  staging: At(buf) @ buf*6144 (2048 = 64x32), Bt(buf) @ buf*6144+2048 (4096 = 128x32)
  //  softmax: P @ 0 (64 x 136), Vs @ 8704 (64 x 136; rows 0-47 V, 48 ones, 49+ garbage)
  __shared__ bf16_t U[17408];
  __shared__ float mixs[768];
  __shared__ float cbw[512];
  __shared__ float rowl[64];

  const int tid = threadIdx.x;
  const int w = tid >> 6, lane = tid & 63;
  const bf16_t* Qp = Qg + (size_t)pd * NPOS * DD;
  const bf16_t* Kp = Kg + (size_t)pd * NPOS * DD;
  const bf16_t* Vp = Vt + (size_t)pd * DD * NPOS + (size_t)h * DHH * NPOS;
  const float* mix = (dir ? mix1 : mix0) + h * DD;
  const int* cnt = CNT + ((pd & ~1) + (1 - dir)) * NPOS;  // to-side counts

  for (int i = tid; i < 768; i += 256) mixs[i] = mix[i] * INV_SCALE;
  for (int i = tid; i < 512; i += 256)
    cbw[i] = cbG[((size_t)pd * NPOS + i) * HH + h] * INV_SCALE + __logf((float)cnt[i]);

  const int wm = w >> 1, wn = w & 1;
  const int lm = lane & 15, lq = lane >> 4;
  const int sr = lane >> 2, sq = lane & 3;

  f32x4 pv[4] = {};

  for (int jt = 0; jt < 4; ++jt) {
    const int j0 = jt * 128;
    __syncthreads();                       // U free (prev jt's PV / init done)

    auto stage = [&](int buf, int k0) {
#pragma unroll
      for (int c = 0; c < 3; ++c) {
        const int issue = w + c * 4;       // wave-uniform
        if (issue < 4)
          g2lds16(Qp + (size_t)(f0 + issue * 16 + sr) * DD + k0 + sq * 8,
                  U + buf * 6144 + issue * 512);
        else {
          const int e = issue - 4;
          g2lds16(Kp + (size_t)(j0 + e * 16 + sr) * DD + k0 + sq * 8,
                  U + buf * 6144 + 2048 + e * 512);
        }
      }
    };

    stage(0, 0);
    f32x4 sa[2][4] = {};
    for (int k0i = 0; k0i < 24; ++k0i) {
      const int cur = k0i & 1;
      const int k0 = k0i * 32;
      __syncthreads();                     // drains cur's g2lds (prefetched last iter)
      if (k0i + 1 < 24) stage(cur ^ 1, k0 + 32);
      const f32x4 mxa = *(const f32x4*)&mixs[k0 + lq * 8];
      const f32x4 mxb = *(const f32x4*)&mixs[k0 + lq * 8 + 4];
      bf16x8 af[2], bfr[4];
#pragma unroll
      for (int i = 0; i < 2; ++i) {
        const bf16x8 q = *(const bf16x8*)(U + cur * 6144 + (wm * 32 + i * 16 + lm) * 32 + lq * 8);
        bf16_t t[8];
#pragma unroll
        for (int e = 0; e < 4; ++e) {
          t[e]     = (bf16_t)((float)q[e] * mxa[e]);
          t[4 + e] = (bf16_t)((float)q[4 + e] * mxb[e]);
        }
        af[i] = *(bf16x8*)t;
      }
#pragma unroll
      for (int j = 0; j < 4; ++j)
        bfr[j] = *(const bf16x8*)(U + cur * 6144 + 2048 + (wn * 64 + j * 16 + lm) * 32 + lq * 8);
#pragma unroll
      for (int i = 0; i < 2; ++i)
#pragma unroll
        for (int j = 0; j < 4; ++j)
          sa[i][j] = __builtin_amdgcn_mfma_f32_16x16x32_bf16(af[i], bfr[j], sa[i][j], 0, 0, 0);
    }
    __syncthreads();                       // staging reads done; U becomes P/Vs

    // P = exp(s + cbw)   (mix pre-scaled, so s already includes INV_SCALE)
#pragma unroll
    for (int j = 0; j < 4; ++j) {
      const int col = wn * 64 + j * 16 + lm;
      const float cb = cbw[j0 + col];
#pragma unroll
      for (int i = 0; i < 2; ++i) {
        const int rbase = wm * 32 + i * 16 + lq * 4;
#pragma unroll
        for (int r = 0; r < 4; ++r)
          U[(rbase + r) * 136 + col] = (bf16_t)__expf(sa[i][j][r] + cb);
      }
    }
    // Vs rows 0..47 = V^T tile, row 48 = ones (denominator trick)
    for (int i = tid; i < 49 * 16; i += 256) {
      const int r = i >> 4, cc = i & 15;
      if (r < 48)
        *(bf16x8*)(U + 8704 + r * 136 + cc * 8) =
            *(const bf16x8*)(Vp + (size_t)r * NPOS + j0 + cc * 8);
      else {
        bf16_t ones[8];
#pragma unroll
        for (int e = 0; e < 8; ++e) ones[e] = (bf16_t)1.f;
        *(bf16x8*)(U + 8704 + 48 * 136 + cc * 8) = *(bf16x8*)ones;
      }
    }
    __syncthreads();

#pragma unroll
    for (int kk = 0; kk < 4; ++kk) {
      const bf16x8 pa = *(const bf16x8*)(U + (w * 16 + lm) * 136 + kk * 32 + lq * 8);
#pragma unroll
      for (int j = 0; j < 4; ++j) {
        const bf16x8 pb = *(const bf16x8*)(U + 8704 + (j * 16 + lm) * 136 + kk * 32 + lq * 8);
        pv[j] = __builtin_amdgcn_mfma_f32_16x16x32_bf16(pa, pb, pv[j], 0, 0, 0);
      }
    }
  }

  // epilogue: col 48 of D (j=3, lm==0) is the row denominator
  if (lm == 0) {
#pragma unroll
    for (int r = 0; r < 4; ++r) rowl[w * 16 + lq * 4 + r] = pv[3][r];
  }
  __syncthreads();
#pragma unroll
  for (int j = 0; j < 3; ++j) {
#pragma unroll
    for (int r = 0; r < 4; ++r) {
      const int fr = w * 16 + lq * 4 + r;
      CTX[((size_t)pd * NPOS + f0 + fr) * DD + h * DHH + j * 16 + lm] =
          (bf16_t)(pv[j][r] / rowl[fr]);
    }
  }
}

// ---------------------------------------------------------------------------
// Residual + LayerNorm + count-weighted mean -> out[b][dir*768 .. +768]
// ---------------------------------------------------------------------------
__global__ __launch_bounds__(256) void ln_mean_kernel(
    const float* __restrict__ hs, const float* __restrict__ XB,
    const int* __restrict__ CNT,
    const float* __restrict__ lng0, const float* __restrict__ lnb0,
    const float* __restrict__ lng1, const float* __restrict__ lnb1,
    float* __restrict__ out) {
  const int blk = blockIdx.x;          // (b*2+dir)*16 + chunk, 96 blocks
  const int chunk = blk & 15;
  const int pd = blk >> 4;
  const int b = pd >> 1, dir = pd & 1;
  const float* lng = dir ? lng1 : lng0;
  const float* lnb = dir ? lnb1 : lnb0;
  const int* cnt = CNT + pd * NPOS;    // from-side counts
  const float* hb = hs + (size_t)b * NPOS * DD;
  const float* xb = XB + (size_t)pd * NPOS * DD;

  __shared__ float wacc[4][DD];
  const int tid = threadIdx.x;
  const int wave = tid >> 6, lane = tid & 63;
  for (int d0 = tid; d0 < 4 * DD; d0 += 256) ((float*)wacc)[d0] = 0.f;
  __syncthreads();

  float lg[12], lb[12];
#pragma unroll
  for (int qd = 0; qd < 12; ++qd) {
    lg[qd] = lng[lane + qd * 64];
    lb[qd] = lnb[lane + qd * 64];
  }

  for (int rr = 0; rr < 8; ++rr) {
    const int p = chunk * 32 + wave * 8 + rr;
    float x[12];
    float s = 0.f, ss = 0.f;
#pragma unroll
    for (int qd = 0; qd < 12; ++qd) {
      const int d0 = lane + qd * 64;
      const float xv = hb[(size_t)p * DD + d0] + xb[(size_t)p * DD + d0];
      x[qd] = xv; s += xv; ss += xv * xv;
    }
#pragma unroll
    for (int o = 1; o < 64; o <<= 1) {
      s += __shfl_xor(s, o);
      ss += __shfl_xor(ss, o);
    }
    const float mu = s * (1.f / 768.f);
    const float var = ss * (1.f / 768.f) - mu * mu;
    const float rstd = rsqrtf(var + LN_EPS);
    const float wgt = (float)cnt[p];
    if (wgt != 0.f) {
#pragma unroll
      for (int qd = 0; qd < 12; ++qd) {
        const int d0 = lane + qd * 64;
        wacc[wave][d0] += wgt * (lg[qd] * (x[qd] - mu) * rstd + lb[qd]);
      }
    }
  }
  __syncthreads();
  for (int d0 = tid; d0 < DD; d0 += 256) {
    const float t = wacc[0][d0] + wacc[1][d0] + wacc[2][d0] + wacc[3][d0];
    atomicAdd(&out[b * 1536 + dir * 768 + d0], t * (1.f / 2048.f));
  }
}

// ---------------------------------------------------------------------------
extern "C" void kernel_launch(void* const* d_in, const int* in_sizes, int n_in,
                              void* d_out, int out_size, void* d_ws, size_t ws_size,
                              hipStream_t stream) {
  const float* hs  = (const float*)d_in[0];
  const int* fpos  = (const int*)d_in[1];
  const int* tpos  = (const int*)d_in[2];

  const float* Wq[2]; const float* Wk[2]; const float* Wcb[2]; const float* Wv[2];
  const float* Wd[2]; const float* mixp[2];
  const float* bv[2]; const float* bd[2]; const float* lng[2]; const float* lnb[2];
  for (int p = 0; p < 2; ++p) {
    const int base = 3 + p * 10;
    Wq[p]   = (const float*)d_in[base + 0];
    Wk[p]   = (const float*)d_in[base + 1];
    Wcb[p]  = (const float*)d_in[base + 2];
    Wv[p]   = (const float*)d_in[base + 3];
    Wd[p]   = (const float*)d_in[base + 4];
    mixp[p] = (const float*)d_in[base + 5];
    bv[p]   = (const float*)d_in[base + 6];
    bd[p]   = (const float*)d_in[base + 7];
    lng[p]  = (const float*)d_in[base + 8];
    lnb[p]  = (const float*)d_in[base + 9];
  }

  char* wsp = (char*)d_ws;
  size_t off = 0;
  auto alloc = [&](size_t bytes) { char* p = wsp + off; off = (off + bytes + 255) & ~(size_t)255; return p; };
  bf16_t* hsb  = (bf16_t*)alloc((size_t)3 * NPOS * DD * 2);
  bf16_t* Wb   = (bf16_t*)alloc((size_t)8 * DD * DD * 2);   // Wq0,Wk0,Wv0,Wd0,Wq1,...
  bf16_t* Qbf  = (bf16_t*)alloc((size_t)6 * NPOS * DD * 2);
  bf16_t* Kbf  = (bf16_t*)alloc((size_t)6 * NPOS * DD * 2);
  bf16_t* VtG  = (bf16_t*)alloc((size_t)6 * DD * NPOS * 2);
  bf16_t* CTXb = (bf16_t*)alloc((size_t)6 * NPOS * DD * 2);
  float*  XB   = (float*) alloc((size_t)6 * NPOS * DD * 4);
  float*  cbG  = (float*) alloc((size_t)6 * NPOS * HH * 4);
  int*    CNTb = (int*)   alloc((size_t)6 * NPOS * 4);

  hipMemsetAsync(d_out, 0, (size_t)out_size * sizeof(float), stream);

  CvtBatch cvb{};
  cvb.d[0] = CvtDesc{hs, hsb, 3 * NPOS * DD / 8};
  const float* wsrc[8] = {Wq[0], Wk[0], Wv[0], Wd[0], Wq[1], Wk[1], Wv[1], Wd[1]};
  for (int i = 0; i < 8; ++i)
    cvb.d[1 + i] = CvtDesc{wsrc[i], Wb + (size_t)i * DD * DD, DD * DD / 8};
  prep<<<774, 256, 0, stream>>>(fpos, tpos, CNTb, cvb, hs, Wcb[0], Wcb[1], cbG);

  // projection GEMMs: Q bf16, K bf16, V bf16-transposed (direct to Vt)
  MBatch gb{};
  int n = 0;
  for (int b = 0; b < 3; ++b)
    for (int p = 0; p < 2; ++p) {
      const int pd = b * 2 + p;
      const bf16_t* A = hsb + (size_t)b * NPOS * DD;
      const size_t o = (size_t)pd * NPOS * DD;
      gb.d[n++] = MDesc{A, Wb + (size_t)(p * 4 + 0) * DD * DD, nullptr, Qbf + o, 1};
      gb.d[n++] = MDesc{A, Wb + (size_t)(p * 4 + 1) * DD * DD, nullptr, Kbf + o, 1};
      gb.d[n++] = MDesc{A, Wb + (size_t)(p * 4 + 2) * DD * DD, bv[p],   VtG + (size_t)pd * DD * NPOS, 2};
    }
  gemm64<<<dim3(48, 18), 256, 0, stream>>>(gb);

  attn_mfma<<<768, 256, 0, stream>>>(Qbf, Kbf, VtG, cbG, CNTb, mixp[0], mixp[1], CTXb);

  MBatch gd{};
  for (int b = 0; b < 3; ++b)
    for (int p = 0; p < 2; ++p) {
      const int pd = b * 2 + p;
      const size_t o = (size_t)pd * NPOS * DD;
      gd.d[pd] = MDesc{CTXb + o, Wb + (size_t)(p * 4 + 3) * DD * DD, bd[p], XB + o, 0};
    }
  gemm64<<<dim3(48, 6), 256, 0, stream>>>(gd);

  ln_mean_kernel<<<96, 256, 0, stream>>>(hs, XB, CNTb, lng[0], lnb[0], lng[1], lnb[1],
                                         (float*)d_out);
}

// Round 5
// 260.280 us; speedup vs baseline: 1.1074x; 1.1074x over previous
//
#include <hip/hip_runtime.h>
#include <math.h>

#define DD 768
#define HH 16
#define DHH 48
#define NPOS 512
#define NIDX 2048
#define INV_SCALE 0.14433756729740643f   // 1/sqrt(768/16)
#define LN_EPS 1e-5f

typedef __bf16 bf16_t;
typedef __bf16 bf16x8 __attribute__((ext_vector_type(8)));
typedef float f32x4 __attribute__((ext_vector_type(4)));

__device__ __forceinline__ void g2lds16(const void* g, void* l) {
  __builtin_amdgcn_global_load_lds((const __attribute__((address_space(1))) void*)g,
                                   (__attribute__((address_space(3))) void*)l, 16, 0, 0);
}
// staging bank-swizzle: lane L of a 16-row issue block fetches 8-elem chunk
// (L&3)^((L>>3)&3); reader at (row, lq) finds chunk lq at position lq^((row>>1)&3).
__device__ __forceinline__ int stg_chunk(int lane) { return (lane & 3) ^ ((lane >> 3) & 3); }
__device__ __forceinline__ int rd_off(int row, int lq) {
  return row * 32 + ((lq ^ ((row >> 1) & 3)) << 3);
}

// ---------------------------------------------------------------------------
// prep: blocks 0-5 hist | rest: fp32->bf16 cvt (src=null -> zero fill)
// ---------------------------------------------------------------------------
struct CvtDesc { const float* src; bf16_t* dst; int n8; };
struct CvtBatch { CvtDesc d[13]; };

__global__ __launch_bounds__(256) void prep(const int* __restrict__ fpos,
                                            const int* __restrict__ tpos,
                                            int* __restrict__ CNT, CvtBatch cvb) {
  const int bid = blockIdx.x;
  const int tid = threadIdx.x;
  __shared__ int shist[NPOS];
  if (bid < 6) {
    const int b = bid >> 1, which = bid & 1;
    const int* src = (which ? tpos : fpos) + b * NIDX;
    for (int i = tid; i < NPOS; i += 256) shist[i] = 0;
    __syncthreads();
    for (int i = tid; i < NIDX; i += 256) atomicAdd(&shist[src[i] & (NPOS - 1)], 1);
    __syncthreads();
    for (int i = tid; i < NPOS; i += 256) CNT[bid * NPOS + i] = shist[i];
    return;
  }
  const CvtDesc de = cvb.d[(bid - 6) >> 6];
  for (int i = ((bid - 6) & 63) * 256 + tid; i < de.n8; i += 64 * 256) {
    bf16_t t[8];
    if (de.src) {
      const f32x4 a = *(const f32x4*)(de.src + (size_t)i * 8);
      const f32x4 b = *(const f32x4*)(de.src + (size_t)i * 8 + 4);
#pragma unroll
      for (int e = 0; e < 4; ++e) { t[e] = (bf16_t)a[e]; t[4 + e] = (bf16_t)b[e]; }
    } else {
#pragma unroll
      for (int e = 0; e < 8; ++e) t[e] = (bf16_t)0.f;
    }
    *(bf16x8*)(de.dst + (size_t)i * 8) = *(bf16x8*)t;
  }
}

// ---------------------------------------------------------------------------
// qmix: Qm[pd][h][f][d] = Q[pd][f][d] * mix[p][h][d] * INV_SCALE   (bf16)
// ---------------------------------------------------------------------------
__global__ __launch_bounds__(256) void qmix(const bf16_t* __restrict__ Qbf,
                                            const float* __restrict__ mix0,
                                            const float* __restrict__ mix1,
                                            bf16_t* __restrict__ Qm) {
  const int idx = blockIdx.x * 256 + threadIdx.x;   // 4,718,592 total
  const int c = idx % 96;
  const int f = (idx / 96) & 511;
  const int h = (idx / (96 * 512)) & 15;
  const int pd = idx / (96 * 512 * 16);
  const bf16x8 q = *(const bf16x8*)(Qbf + ((size_t)pd * NPOS + f) * DD + c * 8);
  const float* m = ((pd & 1) ? mix1 : mix0) + h * DD + c * 8;
  const f32x4 m0 = *(const f32x4*)m;
  const f32x4 m1 = *(const f32x4*)(m + 4);
  bf16_t t[8];
#pragma unroll
  for (int e = 0; e < 4; ++e) {
    t[e]     = (bf16_t)((float)q[e] * m0[e] * INV_SCALE);
    t[4 + e] = (bf16_t)((float)q[4 + e] * m1[e] * INV_SCALE);
  }
  *(bf16x8*)(Qm + ((size_t)(pd * 16 + h) * NPOS + f) * DD + c * 8) = *(bf16x8*)t;
}

// ---------------------------------------------------------------------------
// MFMA GEMM, 64x128 tile, dbuf single-barrier, swizzled staging.
// mode: 0 f32 out | 1 bf16 out | 2 bf16 transposed (C[c*512+r]) |
//       3 K-aug: c<768 -> bf16 C; 768<=c<784 -> f32 cb[r*16+c-768]
// ---------------------------------------------------------------------------
struct MDesc { const bf16_t* A; const bf16_t* B; const float* bias; void* C;
               float* cb; int mode; int ntiles; };
struct MBatch { MDesc d[18]; };

__global__ __launch_bounds__(256, 4) void gemm64(MBatch batch) {
  const MDesc de = batch.d[blockIdx.y];
  const int mt = blockIdx.x & 7, nt = blockIdx.x >> 3;   // 8 x up-to-7
  if (nt >= de.ntiles) return;
  const int m0 = mt * 64, n0 = nt * 128;

  __shared__ bf16_t SA[2][2048];   // [64][32] packed (swizzled chunks)
  __shared__ bf16_t SB[2][4096];   // [128][32]

  const int tid = threadIdx.x;
  const int w = tid >> 6, lane = tid & 63;
  const int wm = w >> 1, wn = w & 1;
  const int lm = lane & 15, lq = lane >> 4;
  const int sr = lane >> 2, sc = stg_chunk(lane);

  f32x4 acc[2][4] = {};

  auto stage = [&](int buf, int k0) {
#pragma unroll
    for (int c = 0; c < 3; ++c) {
      const int issue = w + c * 4;           // 0..11, wave-uniform
      if (issue < 4)
        g2lds16(de.A + (size_t)(m0 + issue * 16 + sr) * 768 + k0 + sc * 8,
                SA[buf] + issue * 512);
      else {
        const int e = issue - 4;
        g2lds16(de.B + (size_t)(n0 + e * 16 + sr) * 768 + k0 + sc * 8,
                SB[buf] + e * 512);
      }
    }
  };

  stage(0, 0);
  for (int k0i = 0; k0i < 24; ++k0i) {
    const int cur = k0i & 1;
    __syncthreads();
    if (k0i + 1 < 24) stage(cur ^ 1, (k0i + 1) * 32);
    bf16x8 af[2], bfr[4];
#pragma unroll
    for (int i = 0; i < 2; ++i)
      af[i] = *(const bf16x8*)(SA[cur] + rd_off(wm * 32 + i * 16 + lm, lq));
#pragma unroll
    for (int j = 0; j < 4; ++j)
      bfr[j] = *(const bf16x8*)(SB[cur] + rd_off(wn * 64 + j * 16 + lm, lq));
#pragma unroll
    for (int i = 0; i < 2; ++i)
#pragma unroll
      for (int j = 0; j < 4; ++j)
        acc[i][j] = __builtin_amdgcn_mfma_f32_16x16x32_bf16(af[i], bfr[j], acc[i][j], 0, 0, 0);
  }

#pragma unroll
  for (int i = 0; i < 2; ++i) {
    const int rbase = m0 + wm * 32 + i * 16 + lq * 4;
#pragma unroll
    for (int j = 0; j < 4; ++j) {
      const int c = n0 + wn * 64 + j * 16 + lm;
      const float bv = (de.bias && c < 768) ? de.bias[c] : 0.f;
#pragma unroll
      for (int r = 0; r < 4; ++r) {
        const float v = acc[i][j][r] + bv;
        if (de.mode == 0)      ((float*)de.C)[(size_t)(rbase + r) * 768 + c] = v;
        else if (de.mode == 1) ((bf16_t*)de.C)[(size_t)(rbase + r) * 768 + c] = (bf16_t)v;
        else if (de.mode == 2) ((bf16_t*)de.C)[(size_t)c * NPOS + rbase + r] = (bf16_t)v;
        else {
          if (c < 768)       ((bf16_t*)de.C)[(size_t)(rbase + r) * 768 + c] = (bf16_t)v;
          else if (c < 784)  de.cb[(size_t)(rbase + r) * 16 + (c - 768)] = v;
        }
      }
    }
  }
}

// ---------------------------------------------------------------------------
// Fused MFMA attention per (pd, h, 64-row f-tile).
// PRE=1: A-tile from precomputed Qm (no VALU mixing). PRE=0: mix at fragment.
// Union LDS; dbuf single-barrier; count folded via log; PV ones-row for denom.
// ---------------------------------------------------------------------------
template <int PRE>
__global__ __launch_bounds__(256, 3) void attn_mfma(
    const bf16_t* __restrict__ Qg, const bf16_t* __restrict__ Qm,
    const bf16_t* __restrict__ Kg, const bf16_t* __restrict__ Vt,
    const float* __restrict__ cbG, const int* __restrict__ CNT,
    const float* __restrict__ mix0, const float* __restrict__ mix1,
    bf16_t* __restrict__ CTX) {
  const int bid = blockIdx.x;             // 6*16*8 = 768
  const int ft = bid & 7, h = (bid >> 3) & 15, pd = bid >> 7;
  const int dir = pd & 1;
  const int f0 = ft * 64;

  __shared__ bf16_t U[17408];
  __shared__ float mixs[PRE ? 4 : 768];
  __shared__ float cbw[512];
  __shared__ float rowl[64];

  const int tid = threadIdx.x;
  const int w = tid >> 6, lane = tid & 63;
  const bf16_t* Qp = PRE ? (Qm + (size_t)(pd * 16 + h) * NPOS * DD)
                         : (Qg + (size_t)pd * NPOS * DD);
  const bf16_t* Kp = Kg + (size_t)pd * NPOS * DD;
  const bf16_t* Vp = Vt + (size_t)pd * DD * NPOS + (size_t)h * DHH * NPOS;
  const int* cnt = CNT + ((pd & ~1) + (1 - dir)) * NPOS;  // to-side counts

  if (!PRE) {
    const float* mix = (dir ? mix1 : mix0) + h * DD;
    for (int i = tid; i < 768; i += 256) mixs[i] = mix[i] * INV_SCALE;
  }
  for (int i = tid; i < 512; i += 256)
    cbw[i] = cbG[((size_t)pd * NPOS + i) * HH + h] * INV_SCALE + __logf((float)cnt[i]);

  const int wm = w >> 1, wn = w & 1;
  const int lm = lane & 15, lq = lane >> 4;
  const int sr = lane >> 2, sc = stg_chunk(lane);

  f32x4 pv[4] = {};

  for (int jt = 0; jt < 4; ++jt) {
    const int j0 = jt * 128;
    __syncthreads();                       // U free (prev jt's PV done)

    auto stage = [&](int buf, int k0) {
#pragma unroll
      for (int c = 0; c < 3; ++c) {
        const int issue = w + c * 4;       // wave-uniform
        if (issue < 4)
          g2lds16(Qp + (size_t)(f0 + issue * 16 + sr) * DD + k0 + sc * 8,
                  U + buf * 6144 + issue * 512);
        else {
          const int e = issue - 4;
          g2lds16(Kp + (size_t)(j0 + e * 16 + sr) * DD + k0 + sc * 8,
                  U + buf * 6144 + 2048 + e * 512);
        }
      }
    };

    stage(0, 0);
    f32x4 sa[2][4] = {};
    for (int k0i = 0; k0i < 24; ++k0i) {
      const int cur = k0i & 1;
      const int k0 = k0i * 32;
      __syncthreads();                     // drains cur's g2lds
      if (k0i + 1 < 24) stage(cur ^ 1, k0 + 32);
      bf16x8 af[2], bfr[4];
#pragma unroll
      for (int i = 0; i < 2; ++i) {
        const int off = cur * 6144 + rd_off(wm * 32 + i * 16 + lm, lq);
        if (PRE) {
          af[i] = *(const bf16x8*)(U + off);
        } else {
          const f32x4 mxa = *(const f32x4*)&mixs[k0 + lq * 8];
          const f32x4 mxb = *(const f32x4*)&mixs[k0 + lq * 8 + 4];
          const bf16x8 q = *(const bf16x8*)(U + off);
          bf16_t t[8];
#pragma unroll
          for (int e = 0; e < 4; ++e) {
            t[e]     = (bf16_t)((float)q[e] * mxa[e]);
            t[4 + e] = (bf16_t)((float)q[4 + e] * mxb[e]);
          }
          af[i] = *(bf16x8*)t;
        }
      }
#pragma unroll
      for (int j = 0; j < 4; ++j)
        bfr[j] = *(const bf16x8*)(U + cur * 6144 + 2048 + rd_off(wn * 64 + j * 16 + lm, lq));
#pragma unroll
      for (int i = 0; i < 2; ++i)
#pragma unroll
        for (int j = 0; j < 4; ++j)
          sa[i][j] = __builtin_amdgcn_mfma_f32_16x16x32_bf16(af[i], bfr[j], sa[i][j], 0, 0, 0);
    }
    __syncthreads();                       // staging reads done; U becomes P/Vs

    // P = exp(s + cbw)   (Qm pre-scaled by INV_SCALE)
#pragma unroll
    for (int j = 0; j < 4; ++j) {
      const int col = wn * 64 + j * 16 + lm;
      const float cb = cbw[j0 + col];
#pragma unroll
      for (int i = 0; i < 2; ++i) {
        const int rbase = wm * 32 + i * 16 + lq * 4;
#pragma unroll
        for (int r = 0; r < 4; ++r)
          U[(rbase + r) * 136 + col] = (bf16_t)__expf(sa[i][j][r] + cb);
      }
    }
    // Vs rows 0..47 = V^T tile, row 48 = ones (denominator trick)
    for (int i = tid; i < 49 * 16; i += 256) {
      const int r = i >> 4, cc = i & 15;
      if (r < 48)
        *(bf16x8*)(U + 8704 + r * 136 + cc * 8) =
            *(const bf16x8*)(Vp + (size_t)r * NPOS + j0 + cc * 8);
      else {
        bf16_t ones[8];
#pragma unroll
        for (int e = 0; e < 8; ++e) ones[e] = (bf16_t)1.f;
        *(bf16x8*)(U + 8704 + 48 * 136 + cc * 8) = *(bf16x8*)ones;
      }
    }
    __syncthreads();

#pragma unroll
    for (int kk = 0; kk < 4; ++kk) {
      const bf16x8 pa = *(const bf16x8*)(U + (w * 16 + lm) * 136 + kk * 32 + lq * 8);
#pragma unroll
      for (int j = 0; j < 4; ++j) {
        const bf16x8 pb = *(const bf16x8*)(U + 8704 + (j * 16 + lm) * 136 + kk * 32 + lq * 8);
        pv[j] = __builtin_amdgcn_mfma_f32_16x16x32_bf16(pa, pb, pv[j], 0, 0, 0);
      }
    }
  }

  if (lm == 0) {
#pragma unroll
    for (int r = 0; r < 4; ++r) rowl[w * 16 + lq * 4 + r] = pv[3][r];
  }
  __syncthreads();
#pragma unroll
  for (int j = 0; j < 3; ++j) {
#pragma unroll
    for (int r = 0; r < 4; ++r) {
      const int fr = w * 16 + lq * 4 + r;
      CTX[((size_t)pd * NPOS + f0 + fr) * DD + h * DHH + j * 16 + lm] =
          (bf16_t)(pv[j][r] / rowl[fr]);
    }
  }
}

// ---------------------------------------------------------------------------
// Residual + LayerNorm + count-weighted mean -> out[b][dir*768 .. +768]
// ---------------------------------------------------------------------------
__global__ __launch_bounds__(256) void ln_mean_kernel(
    const float* __restrict__ hs, const float* __restrict__ XB,
    const int* __restrict__ CNT,
    const float* __restrict__ lng0, const float* __restrict__ lnb0,
    const float* __restrict__ lng1, const float* __restrict__ lnb1,
    float* __restrict__ out) {
  const int blk = blockIdx.x;          // (b*2+dir)*64 + chunk, 384 blocks
  const int chunk = blk & 63;
  const int pd = blk >> 6;
  const int b = pd >> 1, dir = pd & 1;
  const float* lng = dir ? lng1 : lng0;
  const float* lnb = dir ? lnb1 : lnb0;
  const int* cnt = CNT + pd * NPOS;    // from-side counts
  const float* hb = hs + (size_t)b * NPOS * DD;
  const float* xb = XB + (size_t)pd * NPOS * DD;

  __shared__ float wacc[4][DD];
  const int tid = threadIdx.x;
  const int wave = tid >> 6, lane = tid & 63;
  for (int d0 = tid; d0 < 4 * DD; d0 += 256) ((float*)wacc)[d0] = 0.f;
  __syncthreads();

  float lg[12], lb[12];
#pragma unroll
  for (int qd = 0; qd < 12; ++qd) {
    lg[qd] = lng[lane + qd * 64];
    lb[qd] = lnb[lane + qd * 64];
  }

  for (int rr = 0; rr < 2; ++rr) {
    const int p = chunk * 8 + wave * 2 + rr;
    float x[12];
    float s = 0.f, ss = 0.f;
#pragma unroll
    for (int qd = 0; qd < 12; ++qd) {
      const int d0 = lane + qd * 64;
      const float xv = hb[(size_t)p * DD + d0] + xb[(size_t)p * DD + d0];
      x[qd] = xv; s += xv; ss += xv * xv;
    }
#pragma unroll
    for (int o = 1; o < 64; o <<= 1) {
      s += __shfl_xor(s, o);
      ss += __shfl_xor(ss, o);
    }
    const float mu = s * (1.f / 768.f);
    const float var = ss * (1.f / 768.f) - mu * mu;
    const float rstd = rsqrtf(var + LN_EPS);
    const float wgt = (float)cnt[p];
    if (wgt != 0.f) {
#pragma unroll
      for (int qd = 0; qd < 12; ++qd) {
        const int d0 = lane + qd * 64;
        wacc[wave][d0] += wgt * (lg[qd] * (x[qd] - mu) * rstd + lb[qd]);
      }
    }
  }
  __syncthreads();
  for (int d0 = tid; d0 < DD; d0 += 256) {
    const float t = wacc[0][d0] + wacc[1][d0] + wacc[2][d0] + wacc[3][d0];
    atomicAdd(&out[b * 1536 + dir * 768 + d0], t * (1.f / 2048.f));
  }
}

// ---------------------------------------------------------------------------
extern "C" void kernel_launch(void* const* d_in, const int* in_sizes, int n_in,
                              void* d_out, int out_size, void* d_ws, size_t ws_size,
                              hipStream_t stream) {
  const float* hs  = (const float*)d_in[0];
  const int* fpos  = (const int*)d_in[1];
  const int* tpos  = (const int*)d_in[2];

  const float* Wq[2]; const float* Wk[2]; const float* Wcb[2]; const float* Wv[2];
  const float* Wd[2]; const float* mixp[2];
  const float* bv[2]; const float* bd[2]; const float* lng[2]; const float* lnb[2];
  for (int p = 0; p < 2; ++p) {
    const int base = 3 + p * 10;
    Wq[p]   = (const float*)d_in[base + 0];
    Wk[p]   = (const float*)d_in[base + 1];
    Wcb[p]  = (const float*)d_in[base + 2];
    Wv[p]   = (const float*)d_in[base + 3];
    Wd[p]   = (const float*)d_in[base + 4];
    mixp[p] = (const float*)d_in[base + 5];
    bv[p]   = (const float*)d_in[base + 6];
    bd[p]   = (const float*)d_in[base + 7];
    lng[p]  = (const float*)d_in[base + 8];
    lnb[p]  = (const float*)d_in[base + 9];
  }

  char* wsp = (char*)d_ws;
  size_t off = 0;
  auto alloc = [&](size_t bytes) { char* p = wsp + off; off = (off + bytes + 255) & ~(size_t)255; return p; };
  bf16_t* hsb  = (bf16_t*)alloc((size_t)3 * NPOS * DD * 2);
  bf16_t* Wb   = (bf16_t*)alloc((size_t)6 * DD * DD * 2);     // Wq0,Wv0,Wd0,Wq1,Wv1,Wd1
  bf16_t* WkCb = (bf16_t*)alloc((size_t)2 * 896 * DD * 2);    // [Wk;Wcb;pad] per pset
  bf16_t* Qbf  = (bf16_t*)alloc((size_t)6 * NPOS * DD * 2);
  bf16_t* Kbf  = (bf16_t*)alloc((size_t)6 * NPOS * DD * 2);
  bf16_t* VtG  = (bf16_t*)alloc((size_t)6 * DD * NPOS * 2);
  bf16_t* CTXb = (bf16_t*)alloc((size_t)6 * NPOS * DD * 2);
  float*  XB   = (float*) alloc((size_t)6 * NPOS * DD * 4);
  float*  cbG  = (float*) alloc((size_t)6 * NPOS * HH * 4);
  int*    CNTb = (int*)   alloc((size_t)6 * NPOS * 4);
  const size_t qm_bytes = (size_t)6 * HH * NPOS * DD * 2;     // 75.5 MB
  const int use_pre = (off + qm_bytes + 4096 <= ws_size);
  bf16_t* Qm = use_pre ? (bf16_t*)alloc(qm_bytes) : nullptr;

  hipMemsetAsync(d_out, 0, (size_t)out_size * sizeof(float), stream);

  CvtBatch cvb{};
  cvb.d[0] = CvtDesc{hs, hsb, 3 * NPOS * DD / 8};
  for (int p = 0; p < 2; ++p) {
    cvb.d[1 + p * 3] = CvtDesc{Wq[p], Wb + (size_t)(p * 3 + 0) * DD * DD, DD * DD / 8};
    cvb.d[2 + p * 3] = CvtDesc{Wv[p], Wb + (size_t)(p * 3 + 1) * DD * DD, DD * DD / 8};
    cvb.d[3 + p * 3] = CvtDesc{Wd[p], Wb + (size_t)(p * 3 + 2) * DD * DD, DD * DD / 8};
    bf16_t* wk = WkCb + (size_t)p * 896 * DD;
    cvb.d[7 + p * 3] = CvtDesc{Wk[p], wk, DD * DD / 8};
    cvb.d[8 + p * 3] = CvtDesc{Wcb[p], wk + (size_t)768 * DD, 16 * DD / 8};
    cvb.d[9 + p * 3] = CvtDesc{nullptr, wk + (size_t)784 * DD, 112 * DD / 8};
  }
  prep<<<838, 256, 0, stream>>>(fpos, tpos, CNTb, cvb);

  // projection GEMMs: Q bf16, K' (K + content bias), V bf16-transposed
  MBatch gb{};
  int n = 0;
  for (int b = 0; b < 3; ++b)
    for (int p = 0; p < 2; ++p) {
      const int pd = b * 2 + p;
      const bf16_t* A = hsb + (size_t)b * NPOS * DD;
      const size_t o = (size_t)pd * NPOS * DD;
      gb.d[n++] = MDesc{A, Wb + (size_t)(p * 3 + 0) * DD * DD, nullptr, Qbf + o, nullptr, 1, 6};
      gb.d[n++] = MDesc{A, WkCb + (size_t)p * 896 * DD, nullptr, Kbf + o,
                        cbG + (size_t)pd * NPOS * HH, 3, 7};
      gb.d[n++] = MDesc{A, Wb + (size_t)(p * 3 + 1) * DD * DD, bv[p],
                        VtG + (size_t)pd * DD * NPOS, nullptr, 2, 6};
    }
  gemm64<<<dim3(56, 18), 256, 0, stream>>>(gb);

  if (use_pre) {
    qmix<<<18432, 256, 0, stream>>>(Qbf, mixp[0], mixp[1], Qm);
    attn_mfma<1><<<768, 256, 0, stream>>>(Qbf, Qm, Kbf, VtG, cbG, CNTb,
                                          mixp[0], mixp[1], CTXb);
  } else {
    attn_mfma<0><<<768, 256, 0, stream>>>(Qbf, Qbf, Kbf, VtG, cbG, CNTb,
                                          mixp[0], mixp[1], CTXb);
  }

  MBatch gd{};
  for (int b = 0; b < 3; ++b)
    for (int p = 0; p < 2; ++p) {
      const int pd = b * 2 + p;
      const size_t o = (size_t)pd * NPOS * DD;
      gd.d[pd] = MDesc{CTXb + o, Wb + (size_t)(p * 3 + 2) * DD * DD, bd[p],
                       XB + o, nullptr, 0, 6};
    }
  gemm64<<<dim3(56, 6), 256, 0, stream>>>(gd);

  ln_mean_kernel<<<384, 256, 0, stream>>>(hs, XB, CNTb, lng[0], lnb[0], lng[1], lnb[1],
                                          (float*)d_out);
}